// Round 4
// baseline (9793.168 us; speedup 1.0000x reference)
//
#include <hip/hip_runtime.h>
#include <hip/hip_bf16.h>

#define BB 4
#define SS 2048
#define FF 512
#define HH 8
#define EPSV 1e-5f

// ============ Kernel 1: QKV projection (batched fp32 GEMM) ============
// Chunk-local: bh in [0, nb*HH); real batch = b_base + bh/HH.
// grid (FF/64, SS/64, 3*nb*HH), block 256
__global__ __launch_bounds__(256)
void proj_kernel(const float* __restrict__ x, const float* __restrict__ Wq,
                 const float* __restrict__ Wk, const float* __restrict__ Wv,
                 float* __restrict__ Q, float* __restrict__ K, float* __restrict__ V,
                 int b_base, int nbh)
{
    __shared__ float As[16][68];   // [k][m] transposed
    __shared__ float Bs[16][68];   // [k][n]

    const int t = threadIdx.x;
    const int n0 = blockIdx.x * 64;
    const int m0 = blockIdx.y * 64;
    const int which = blockIdx.z / nbh;
    const int bh = blockIdx.z % nbh;
    const int h = bh % HH;

    const float* W = (which == 0) ? Wq : (which == 1) ? Wk : Wv;
    float* C = (which == 0) ? Q : (which == 1) ? K : V;

    const float* xb = x + (size_t)(b_base + bh / HH) * SS * FF;
    const float* Wh = W + (size_t)h * FF * FF;
    float* Cb = C + (size_t)bh * SS * FF;

    const int tm = t >> 4, tn = t & 15;           // 16x16 threads, 4x4 micro
    const int ar = t >> 2, ac = (t & 3) << 2;     // A load: 64 rows x 4 float4-cols
    const int br = t >> 4, bc = (t & 15) << 2;    // B load: 16 rows x 16 float4-cols

    float acc[4][4] = {};

    for (int k0 = 0; k0 < FF; k0 += 16) {
        float4 av = *(const float4*)&xb[(size_t)(m0 + ar) * FF + k0 + ac];
        float4 bv = *(const float4*)&Wh[(size_t)(k0 + br) * FF + n0 + bc];
        __syncthreads();
        As[ac + 0][ar] = av.x; As[ac + 1][ar] = av.y;
        As[ac + 2][ar] = av.z; As[ac + 3][ar] = av.w;
        *(float4*)&Bs[br][bc] = bv;
        __syncthreads();
        #pragma unroll
        for (int kk = 0; kk < 16; ++kk) {
            float4 a4 = *(const float4*)&As[kk][tm * 4];
            float4 b4 = *(const float4*)&Bs[kk][tn * 4];
            const float aa[4] = {a4.x, a4.y, a4.z, a4.w};
            const float bb[4] = {b4.x, b4.y, b4.z, b4.w};
            #pragma unroll
            for (int i = 0; i < 4; ++i)
                #pragma unroll
                for (int j = 0; j < 4; ++j)
                    acc[i][j] = fmaf(aa[i], bb[j], acc[i][j]);
        }
    }
    #pragma unroll
    for (int i = 0; i < 4; ++i) {
        float4 o = make_float4(acc[i][0], acc[i][1], acc[i][2], acc[i][3]);
        *(float4*)&Cb[(size_t)(m0 + tm * 4 + i) * FF + n0 + tn * 4] = o;
    }
}

// ============ Kernel 2: fused attention (flash-style, fp32) ============
// grid (SS/32, nb*HH), block 256. Q-tile 32 rows resident; K/V tiles of 16 rows.
__global__ __launch_bounds__(256)
void attn_kernel(const float* __restrict__ x, const float* __restrict__ Q,
                 const float* __restrict__ K, const float* __restrict__ V,
                 float* __restrict__ Z, int b_base)
{
    __shared__ float Qs[32][516];      // 66048 B
    __shared__ float KVs[16][516];     // 33024 B (K, then V)
    __shared__ float Pp[8][32][17];    // 17408 B  score partials per f-group
    __shared__ float Pr[32][17];       //  2176 B  probs
    __shared__ float mrow[32], lrow[32], srow[32];

    const int t = threadIdx.x;
    const int s0 = blockIdx.x * 32;
    const int bh = blockIdx.y;                 // chunk-local

    const float* Qp = Q + ((size_t)bh * SS + s0) * FF;
    const float* Kp = K + (size_t)bh * SS * FF;
    const float* Vp = V + (size_t)bh * SS * FF;

    // load Q tile (32x512 f32), linear-coalesced
    #pragma unroll
    for (int j = 0; j < 16; ++j) {
        int idx = t + 256 * j;
        int r = idx >> 7, c = (idx & 127) << 2;
        *(float4*)&Qs[r][c] = *(const float4*)&Qp[(size_t)r * FF + c];
    }
    if (t < 32) { mrow[t] = -3.0e38f; lrow[t] = 0.0f; }

    // score-phase ids: 8 f-groups x (8 tq x 4 tk), 4x4 micro over rows {r,r+8i}/{k,k+4j}
    const int g  = t >> 5;
    const int tq = (t >> 2) & 7;
    const int tk = t & 3;
    // PV/epilogue ids: 2 q-rows x 32 f (f = fs*4 + c*64)
    const int q0 = (t >> 4) << 1;
    const int fs = t & 15;

    float acc[2][32] = {};

    for (int kt = 0; kt < SS / 16; ++kt) {
        const float* Kt = Kp + (size_t)kt * 16 * FF;
        const float* Vt = Vp + (size_t)kt * 16 * FF;
        __syncthreads();                 // prev PV done with KVs
        #pragma unroll
        for (int j = 0; j < 8; ++j) {
            int idx = t + 256 * j;
            int r = idx >> 7, c = (idx & 127) << 2;
            *(float4*)&KVs[r][c] = *(const float4*)&Kt[(size_t)r * FF + c];
        }
        __syncthreads();                 // K ready
        // ---- scores: partial dot over f in [g*64, g*64+64) ----
        {
            float sacc[4][4] = {};
            #pragma unroll
            for (int f4 = 0; f4 < 16; ++f4) {
                const int f = g * 64 + f4 * 4;
                float4 qv[4], kv[4];
                #pragma unroll
                for (int i = 0; i < 4; ++i) qv[i] = *(const float4*)&Qs[tq + 8 * i][f];
                #pragma unroll
                for (int j = 0; j < 4; ++j) kv[j] = *(const float4*)&KVs[tk + 4 * j][f];
                #pragma unroll
                for (int i = 0; i < 4; ++i)
                    #pragma unroll
                    for (int j = 0; j < 4; ++j) {
                        sacc[i][j] = fmaf(qv[i].x, kv[j].x, sacc[i][j]);
                        sacc[i][j] = fmaf(qv[i].y, kv[j].y, sacc[i][j]);
                        sacc[i][j] = fmaf(qv[i].z, kv[j].z, sacc[i][j]);
                        sacc[i][j] = fmaf(qv[i].w, kv[j].w, sacc[i][j]);
                    }
            }
            #pragma unroll
            for (int i = 0; i < 4; ++i)
                #pragma unroll
                for (int j = 0; j < 4; ++j)
                    Pp[g][tq + 8 * i][tk + 4 * j] = sacc[i][j];
        }
        __syncthreads();                 // Pp ready, KVs free
        // ---- V load (overwrites KVs) + online-softmax bookkeeping ----
        #pragma unroll
        for (int j = 0; j < 8; ++j) {
            int idx = t + 256 * j;
            int r = idx >> 7, c = (idx & 127) << 2;
            *(float4*)&KVs[r][c] = *(const float4*)&Vt[(size_t)r * FF + c];
        }
        {
            const int r = t >> 3, jj = t & 7;   // row r, lanes jj own ki=2jj,2jj+1
            float sa = 0.0f, sb = 0.0f;
            #pragma unroll
            for (int g2 = 0; g2 < 8; ++g2) {
                sa += Pp[g2][r][2 * jj + 0];
                sb += Pp[g2][r][2 * jj + 1];
            }
            float mx = fmaxf(sa, sb);
            #pragma unroll
            for (int w = 1; w < 8; w <<= 1) mx = fmaxf(mx, __shfl_xor(mx, w, 8));
            const float mold = mrow[r];
            const float mnew = fmaxf(mold, mx);
            const float pa = __expf(sa - mnew);
            const float pb = __expf(sb - mnew);
            float ls = pa + pb;
            #pragma unroll
            for (int w = 1; w < 8; w <<= 1) ls += __shfl_xor(ls, w, 8);
            Pr[r][2 * jj + 0] = pa;
            Pr[r][2 * jj + 1] = pb;
            if (jj == 0) {
                const float sc = __expf(mold - mnew);
                srow[r] = sc;
                lrow[r] = lrow[r] * sc + ls;
                mrow[r] = mnew;
            }
        }
        __syncthreads();                 // V + Pr + srow ready
        // ---- PV: acc = acc*scale + P @ V ----
        {
            const float sc0 = srow[q0], sc1 = srow[q0 + 1];
            #pragma unroll
            for (int u = 0; u < 32; ++u) { acc[0][u] *= sc0; acc[1][u] *= sc1; }
            #pragma unroll
            for (int ki = 0; ki < 16; ++ki) {
                const float p0 = Pr[q0][ki], p1 = Pr[q0 + 1][ki];
                #pragma unroll
                for (int c = 0; c < 8; ++c) {
                    float4 vv = *(const float4*)&KVs[ki][fs * 4 + c * 64];
                    acc[0][c * 4 + 0] = fmaf(p0, vv.x, acc[0][c * 4 + 0]);
                    acc[0][c * 4 + 1] = fmaf(p0, vv.y, acc[0][c * 4 + 1]);
                    acc[0][c * 4 + 2] = fmaf(p0, vv.z, acc[0][c * 4 + 2]);
                    acc[0][c * 4 + 3] = fmaf(p0, vv.w, acc[0][c * 4 + 3]);
                    acc[1][c * 4 + 0] = fmaf(p1, vv.x, acc[1][c * 4 + 0]);
                    acc[1][c * 4 + 1] = fmaf(p1, vv.y, acc[1][c * 4 + 1]);
                    acc[1][c * 4 + 2] = fmaf(p1, vv.z, acc[1][c * 4 + 2]);
                    acc[1][c * 4 + 3] = fmaf(p1, vv.w, acc[1][c * 4 + 3]);
                }
            }
        }
    }
    // epilogue: Z = acc/l + x  (per-head residual folded in)
    {
        const int b = b_base + bh / HH;
        const float li0 = 1.0f / lrow[q0];
        const float li1 = 1.0f / lrow[q0 + 1];
        const float* xp = x + ((size_t)b * SS + s0) * FF;
        float* Zp = Z + ((size_t)bh * SS + s0) * FF;
        #pragma unroll
        for (int i = 0; i < 2; ++i) {
            const float li = i ? li1 : li0;
            #pragma unroll
            for (int c = 0; c < 8; ++c) {
                const int f = fs * 4 + c * 64;
                float4 xv = *(const float4*)&xp[(size_t)(q0 + i) * FF + f];
                float4 o;
                o.x = fmaf(acc[i][c * 4 + 0], li, xv.x);
                o.y = fmaf(acc[i][c * 4 + 1], li, xv.y);
                o.z = fmaf(acc[i][c * 4 + 2], li, xv.z);
                o.w = fmaf(acc[i][c * 4 + 3], li, xv.w);
                *(float4*)&Zp[(size_t)(q0 + i) * FF + f] = o;
            }
        }
    }
}

// ============ Kernel 3: joiner GEMM + residual + LayerNorm ============
// Chunk-local rows: grid (nb*SS/32), block 256. Z is chunk-local, x/out global.
__global__ __launch_bounds__(256)
void joiner_ln_kernel(const float* __restrict__ x, const float* __restrict__ Z,
                      const float* __restrict__ Wj, const float* __restrict__ gamma,
                      const float* __restrict__ beta, float* __restrict__ out,
                      int b_base)
{
    __shared__ float AsT[16][33];     // [k][m]
    __shared__ float Bs[16][516];     // [k][n] full 512-wide

    const int t = threadIdx.x;
    const int lm0 = blockIdx.x * 32;          // chunk-local row
    const int bl = lm0 / SS;                  // chunk-local batch
    const int s0 = lm0 % SS;
    const size_t gm0 = (size_t)(b_base + bl) * SS + s0;   // global row

    const int qg = t >> 5;    // 0..7 -> rows qg*4..+3
    const int fs = t & 31;    // f = fs*4 + c*128

    float acc[4][16] = {};

    for (int k0 = 0; k0 < HH * FF; k0 += 16) {
        const int h = k0 >> 9;
        const int f0 = k0 & 511;
        __syncthreads();
        {   // A: Zcat rows lm0..lm0+31, cols k0..k0+15 (= head h, feats f0..f0+15)
            const int r = t >> 3, c2 = (t & 7) << 1;
            float2 av = *(const float2*)&Z[(((size_t)(bl * HH + h) * SS) + s0 + r) * FF + f0 + c2];
            AsT[c2 + 0][r] = av.x;
            AsT[c2 + 1][r] = av.y;
        }
        {   // B: Wj rows k0..k0+15 x 512 (contiguous 32 KB)
            const float* Wp = Wj + (size_t)k0 * FF;
            #pragma unroll
            for (int j = 0; j < 8; ++j) {
                int idx = t + 256 * j;
                int r = idx >> 7, c = (idx & 127) << 2;
                *(float4*)&Bs[r][c] = *(const float4*)&Wp[(size_t)r * FF + c];
            }
        }
        __syncthreads();
        #pragma unroll
        for (int kk = 0; kk < 16; ++kk) {
            const float a0 = AsT[kk][qg * 4 + 0];
            const float a1 = AsT[kk][qg * 4 + 1];
            const float a2 = AsT[kk][qg * 4 + 2];
            const float a3 = AsT[kk][qg * 4 + 3];
            #pragma unroll
            for (int c = 0; c < 4; ++c) {
                float4 bv = *(const float4*)&Bs[kk][fs * 4 + c * 128];
                acc[0][c * 4 + 0] = fmaf(a0, bv.x, acc[0][c * 4 + 0]);
                acc[0][c * 4 + 1] = fmaf(a0, bv.y, acc[0][c * 4 + 1]);
                acc[0][c * 4 + 2] = fmaf(a0, bv.z, acc[0][c * 4 + 2]);
                acc[0][c * 4 + 3] = fmaf(a0, bv.w, acc[0][c * 4 + 3]);
                acc[1][c * 4 + 0] = fmaf(a1, bv.x, acc[1][c * 4 + 0]);
                acc[1][c * 4 + 1] = fmaf(a1, bv.y, acc[1][c * 4 + 1]);
                acc[1][c * 4 + 2] = fmaf(a1, bv.z, acc[1][c * 4 + 2]);
                acc[1][c * 4 + 3] = fmaf(a1, bv.w, acc[1][c * 4 + 3]);
                acc[2][c * 4 + 0] = fmaf(a2, bv.x, acc[2][c * 4 + 0]);
                acc[2][c * 4 + 1] = fmaf(a2, bv.y, acc[2][c * 4 + 1]);
                acc[2][c * 4 + 2] = fmaf(a2, bv.z, acc[2][c * 4 + 2]);
                acc[2][c * 4 + 3] = fmaf(a2, bv.w, acc[2][c * 4 + 3]);
                acc[3][c * 4 + 0] = fmaf(a3, bv.x, acc[3][c * 4 + 0]);
                acc[3][c * 4 + 1] = fmaf(a3, bv.y, acc[3][c * 4 + 1]);
                acc[3][c * 4 + 2] = fmaf(a3, bv.z, acc[3][c * 4 + 2]);
                acc[3][c * 4 + 3] = fmaf(a3, bv.w, acc[3][c * 4 + 3]);
            }
        }
    }
    // residual + LayerNorm (biased variance, eps inside rsqrt)
    float s1[4] = {0, 0, 0, 0}, s2[4] = {0, 0, 0, 0};
    #pragma unroll
    for (int i = 0; i < 4; ++i) {
        #pragma unroll
        for (int c = 0; c < 4; ++c) {
            const int f = fs * 4 + c * 128;
            float4 xv = *(const float4*)&x[(gm0 + qg * 4 + i) * FF + f];
            acc[i][c * 4 + 0] += xv.x;
            acc[i][c * 4 + 1] += xv.y;
            acc[i][c * 4 + 2] += xv.z;
            acc[i][c * 4 + 3] += xv.w;
            #pragma unroll
            for (int j = 0; j < 4; ++j) {
                s1[i] += acc[i][c * 4 + j];
                s2[i] += acc[i][c * 4 + j] * acc[i][c * 4 + j];
            }
        }
    }
    #pragma unroll
    for (int i = 0; i < 4; ++i) {
        #pragma unroll
        for (int w = 1; w < 32; w <<= 1) {
            s1[i] += __shfl_xor(s1[i], w, 32);
            s2[i] += __shfl_xor(s2[i], w, 32);
        }
        const float mu = s1[i] * (1.0f / FF);
        float var = s2[i] * (1.0f / FF) - mu * mu;
        var = fmaxf(var, 0.0f);
        const float rs = rsqrtf(var + EPSV);
        #pragma unroll
        for (int c = 0; c < 4; ++c) {
            const int f = fs * 4 + c * 128;
            float4 gv = *(const float4*)&gamma[f];
            float4 bv = *(const float4*)&beta[f];
            float4 o;
            o.x = (acc[i][c * 4 + 0] - mu) * rs * gv.x + bv.x;
            o.y = (acc[i][c * 4 + 1] - mu) * rs * gv.y + bv.y;
            o.z = (acc[i][c * 4 + 2] - mu) * rs * gv.z + bv.z;
            o.w = (acc[i][c * 4 + 3] - mu) * rs * gv.w + bv.w;
            *(float4*)&out[(gm0 + qg * 4 + i) * FF + f] = o;
        }
    }
}

extern "C" void kernel_launch(void* const* d_in, const int* in_sizes, int n_in,
                              void* d_out, int out_size, void* d_ws, size_t ws_size,
                              hipStream_t stream)
{
    const float* x     = (const float*)d_in[0];
    const float* Wq    = (const float*)d_in[1];
    const float* Wk    = (const float*)d_in[2];
    const float* Wv    = (const float*)d_in[3];
    const float* Wj    = (const float*)d_in[4];
    const float* gamma = (const float*)d_in[5];
    const float* beta  = (const float*)d_in[6];
    float* out = (float*)d_out;

    // Workspace per batch-chunk of nb batches: Q|K|V|Z, each [nb,H,S,F] f32.
    // Choose the largest nb (<= BB) that fits in ws_size; loop over chunks.
    const size_t per_b = (size_t)HH * SS * FF;           // elements per batch per buffer
    const size_t bytes_per_batch = 4 * per_b * sizeof(float);   // 134.2 MB
    int nb = (int)(ws_size / bytes_per_batch);
    if (nb > BB) nb = BB;
    if (nb < 1) nb = 1;   // nothing else we can do; best effort

    for (int b_base = 0; b_base < BB; b_base += nb) {
        int cb = BB - b_base < nb ? BB - b_base : nb;    // batches this chunk
        const size_t per = (size_t)cb * per_b;
        float* Q = (float*)d_ws;
        float* K = Q + per;
        float* V = K + per;
        float* Z = V + per;
        const int nbh = cb * HH;

        dim3 gp(FF / 64, SS / 64, 3 * nbh);
        proj_kernel<<<gp, 256, 0, stream>>>(x, Wq, Wk, Wv, Q, K, V, b_base, nbh);

        dim3 ga(SS / 32, nbh);
        attn_kernel<<<ga, 256, 0, stream>>>(x, Q, K, V, Z, b_base);

        joiner_ln_kernel<<<(cb * SS) / 32, 256, 0, stream>>>(x, Z, Wj, gamma, beta, out, b_base);
    }
}

// Round 7
// 1989.338 us; speedup vs baseline: 4.9228x; 4.9228x over previous
//
#include <hip/hip_runtime.h>
#include <hip/hip_bf16.h>

#define BB 4
#define SS 2048
#define FF 512
#define HH 8
#define EPSV 1e-5f

typedef __attribute__((ext_vector_type(8))) short bf16x8;
typedef __attribute__((ext_vector_type(4))) float f32x4;

#define MFMA_B16(a,b,c) __builtin_amdgcn_mfma_f32_16x16x32_bf16((a),(b),(c),0,0,0)

__device__ __forceinline__ short f2bf(float v) {
    union { __hip_bfloat16 b; short s; } u; u.b = __float2bfloat16(v); return u.s;
}
__device__ __forceinline__ float bf2f(short s) {
    union { short s; __hip_bfloat16 b; } u; u.s = s; return __bfloat162float(u.b);
}
__device__ __forceinline__ unsigned pack2(short a, short b) {
    return (unsigned)(unsigned short)a | ((unsigned)(unsigned short)b << 16);
}

// ============ prep: split x into hi/lo bf16 planes ============
__global__ __launch_bounds__(256)
void prep_x_kernel(const float* __restrict__ x, short* __restrict__ xhi, short* __restrict__ xlo)
{
    const int n4 = BB*SS*FF/4;
    for (int i = blockIdx.x*256 + threadIdx.x; i < n4; i += gridDim.x*256) {
        float4 v = *(const float4*)&x[(size_t)i*4];
        short h0=f2bf(v.x),h1=f2bf(v.y),h2=f2bf(v.z),h3=f2bf(v.w);
        uint2 ph, pl;
        ph.x = pack2(h0,h1); ph.y = pack2(h2,h3);
        pl.x = pack2(f2bf(v.x-bf2f(h0)), f2bf(v.y-bf2f(h1)));
        pl.y = pack2(f2bf(v.z-bf2f(h2)), f2bf(v.w-bf2f(h3)));
        *(uint2*)&xhi[(size_t)i*4] = ph;
        *(uint2*)&xlo[(size_t)i*4] = pl;
    }
}

// ============ prep: transpose fp32 [R][C] -> hi/lo bf16 [C][R], per mat z ============
__global__ __launch_bounds__(256)
void prep_t_kernel(const float* __restrict__ in, short* __restrict__ oh, short* __restrict__ ol,
                   int R, int C)
{
    __shared__ float Ts[64][68];
    const int t = threadIdx.x;
    const int c0 = blockIdx.x*64, r0 = blockIdx.y*64;
    const size_t mo = (size_t)blockIdx.z * R * C;
    #pragma unroll
    for (int i = 0; i < 4; ++i) {
        int idx = t + 256*i;
        int rr = idx >> 4, c4 = (idx & 15)*4;
        float4 v = *(const float4*)&in[mo + (size_t)(r0+rr)*C + c0 + c4];
        Ts[rr][c4] = v.x; Ts[rr][c4+1] = v.y; Ts[rr][c4+2] = v.z; Ts[rr][c4+3] = v.w;
    }
    __syncthreads();
    #pragma unroll
    for (int i = 0; i < 4; ++i) {
        int idx = t + 256*i;
        int cc = idx >> 4, k4 = (idx & 15)*4;
        short h[4], l[4];
        #pragma unroll
        for (int j = 0; j < 4; ++j) {
            float v = Ts[k4+j][cc];
            h[j] = f2bf(v); l[j] = f2bf(v - bf2f(h[j]));
        }
        uint2 ph, pl;
        ph.x = pack2(h[0],h[1]); ph.y = pack2(h[2],h[3]);
        pl.x = pack2(l[0],l[1]); pl.y = pack2(l[2],l[3]);
        *(uint2*)&oh[mo + (size_t)(c0+cc)*R + r0 + k4] = ph;
        *(uint2*)&ol[mo + (size_t)(c0+cc)*R + r0 + k4] = pl;
    }
}

// ============ Kernel 1: QKV projection, split-bf16 MFMA ============
// grid (FF/128=4, SS/128=16, 3*nbh), block 256 (4 waves, 2x2 of 64x64)
__global__ __launch_bounds__(256,1)
void proj_kernel(const short* __restrict__ xhi, const short* __restrict__ xlo,
                 const short* __restrict__ Wth, const short* __restrict__ Wtl,
                 short* __restrict__ Qhi, short* __restrict__ Qlo,
                 short* __restrict__ Khi, short* __restrict__ Klo,
                 short* __restrict__ Vt, int b_base, int nbh)
{
    __shared__ short Ah[128][40], Al[128][40];   // [m][k]
    __shared__ short Bh[128][40], Bl[128][40];   // [n][k] (W^T)
    const int t = threadIdx.x, lane = t & 63, w = t >> 6;
    const int l15 = lane & 15, l16 = lane >> 4;
    const int wm = (w >> 1)*64, wn = (w & 1)*64;
    const int n0 = blockIdx.x*128, m0 = blockIdx.y*128;
    const int which = blockIdx.z / nbh;
    const int bh = blockIdx.z % nbh;
    const int h = bh % HH;
    const short* xh = xhi + (size_t)(b_base + bh/HH)*SS*FF;
    const short* xl = xlo + (size_t)(b_base + bh/HH)*SS*FF;
    const short* Bgh = Wth + (size_t)(which*HH + h)*FF*FF;
    const short* Bgl = Wtl + (size_t)(which*HH + h)*FF*FF;

    f32x4 acc[4][4] = {};

    for (int k0 = 0; k0 < FF; k0 += 32) {
        __syncthreads();
        #pragma unroll
        for (int i = 0; i < 2; ++i) {
            int idx = t + 256*i;
            int row = idx >> 2, c8 = (idx & 3)*8;
            *(bf16x8*)&Ah[row][c8] = *(const bf16x8*)&xh[(size_t)(m0+row)*FF + k0 + c8];
            *(bf16x8*)&Al[row][c8] = *(const bf16x8*)&xl[(size_t)(m0+row)*FF + k0 + c8];
            *(bf16x8*)&Bh[row][c8] = *(const bf16x8*)&Bgh[(size_t)(n0+row)*FF + k0 + c8];
            *(bf16x8*)&Bl[row][c8] = *(const bf16x8*)&Bgl[(size_t)(n0+row)*FF + k0 + c8];
        }
        __syncthreads();
        bf16x8 a_h[4], a_l[4], b_h[4], b_l[4];
        #pragma unroll
        for (int mf = 0; mf < 4; ++mf) {
            a_h[mf] = *(const bf16x8*)&Ah[wm + mf*16 + l15][l16*8];
            a_l[mf] = *(const bf16x8*)&Al[wm + mf*16 + l15][l16*8];
        }
        #pragma unroll
        for (int nf = 0; nf < 4; ++nf) {
            b_h[nf] = *(const bf16x8*)&Bh[wn + nf*16 + l15][l16*8];
            b_l[nf] = *(const bf16x8*)&Bl[wn + nf*16 + l15][l16*8];
        }
        #pragma unroll
        for (int mf = 0; mf < 4; ++mf)
        #pragma unroll
        for (int nf = 0; nf < 4; ++nf) {
            acc[mf][nf] = MFMA_B16(a_h[mf], b_h[nf], acc[mf][nf]);
            acc[mf][nf] = MFMA_B16(a_h[mf], b_l[nf], acc[mf][nf]);
            acc[mf][nf] = MFMA_B16(a_l[mf], b_h[nf], acc[mf][nf]);
        }
    }
    if (which < 2) {
        short* Ph = ((which==0) ? Qhi : Khi) + (size_t)bh*SS*FF;
        short* Pl = ((which==0) ? Qlo : Klo) + (size_t)bh*SS*FF;
        #pragma unroll
        for (int mf = 0; mf < 4; ++mf)
        #pragma unroll
        for (int nf = 0; nf < 4; ++nf)
        #pragma unroll
        for (int r = 0; r < 4; ++r) {
            int rw = m0 + wm + mf*16 + l16*4 + r;
            int cl = n0 + wn + nf*16 + l15;
            float v = acc[mf][nf][r];
            short hh = f2bf(v);
            Ph[(size_t)rw*FF + cl] = hh;
            Pl[(size_t)rw*FF + cl] = f2bf(v - bf2f(hh));
        }
    } else {
        short* Vp = Vt + (size_t)bh*FF*SS;   // [f][s]
        #pragma unroll
        for (int mf = 0; mf < 4; ++mf)
        #pragma unroll
        for (int nf = 0; nf < 4; ++nf) {
            int cl = n0 + wn + nf*16 + l15;       // feature
            int rw = m0 + wm + mf*16 + l16*4;     // s base (4 consecutive)
            uint2 pk;
            pk.x = pack2(f2bf(acc[mf][nf][0]), f2bf(acc[mf][nf][1]));
            pk.y = pack2(f2bf(acc[mf][nf][2]), f2bf(acc[mf][nf][3]));
            *(uint2*)&Vp[(size_t)cl*SS + rw] = pk;
        }
    }
}

// ============ Kernel 2: flash attention, split-bf16 QK + bf16 PV ============
// grid (SS/64=32, nbh), block 256. Q hi/lo in registers (wave owns 16 q-rows).
__global__ __launch_bounds__(256,1)
void attn_kernel(const float* __restrict__ x,
                 const short* __restrict__ Qhi, const short* __restrict__ Qlo,
                 const short* __restrict__ Khi, const short* __restrict__ Klo,
                 const short* __restrict__ VtG,
                 short* __restrict__ Zhi, short* __restrict__ Zlo, int b_base)
{
    __shared__ short Ksh[32][520], Ksl[32][520];  // K tile hi/lo [key][f]
    __shared__ short Vts[512][40];                // V^T tile [f][kv]
    __shared__ float Ps[64][33];                  // scores
    __shared__ short Pb[64][40];                  // probs bf16
    __shared__ float mrow[64], lrow[64], srow[64];

    const int t = threadIdx.x, lane = t & 63, w = t >> 6;
    const int l15 = lane & 15, l16 = lane >> 4;
    const int s0 = blockIdx.x * 64;
    const int bh = blockIdx.y;

    const size_t qoff = ((size_t)bh*SS + s0 + w*16 + l15)*FF;
    bf16x8 qh[16], ql[16];
    #pragma unroll
    for (int ks = 0; ks < 16; ++ks) {
        qh[ks] = *(const bf16x8*)&Qhi[qoff + ks*32 + l16*8];
        ql[ks] = *(const bf16x8*)&Qlo[qoff + ks*32 + l16*8];
    }
    if (t < 64) { mrow[t] = -3.0e38f; lrow[t] = 0.0f; }

    const short* Kh = Khi + (size_t)bh*SS*FF;
    const short* Kl = Klo + (size_t)bh*SS*FF;
    const short* Vg = VtG + (size_t)bh*FF*SS;

    f32x4 o[4][8] = {};

    for (int kt = 0; kt < SS/32; ++kt) {
        const int k0 = kt*32;
        // ---- stage K hi/lo ----
        #pragma unroll
        for (int i = 0; i < 8; ++i) {
            int idx = t + 256*i;
            int row = idx >> 6, c8 = (idx & 63)*8;
            *(bf16x8*)&Ksh[row][c8] = *(const bf16x8*)&Kh[(size_t)(k0+row)*FF + c8];
            *(bf16x8*)&Ksl[row][c8] = *(const bf16x8*)&Kl[(size_t)(k0+row)*FF + c8];
        }
        __syncthreads();                              // (1) K ready
        // ---- QK^T: D = Q . K^T, split-bf16 (hh + hl + lh) ----
        f32x4 shh[2] = {}, shl[2] = {}, slh[2] = {};
        #pragma unroll
        for (int ks = 0; ks < 16; ++ks) {
            bf16x8 b0h = *(const bf16x8*)&Ksh[l15][ks*32 + l16*8];
            bf16x8 b0l = *(const bf16x8*)&Ksl[l15][ks*32 + l16*8];
            bf16x8 b1h = *(const bf16x8*)&Ksh[16 + l15][ks*32 + l16*8];
            bf16x8 b1l = *(const bf16x8*)&Ksl[16 + l15][ks*32 + l16*8];
            shh[0] = MFMA_B16(qh[ks], b0h, shh[0]);
            shl[0] = MFMA_B16(qh[ks], b0l, shl[0]);
            slh[0] = MFMA_B16(ql[ks], b0h, slh[0]);
            shh[1] = MFMA_B16(qh[ks], b1h, shh[1]);
            shl[1] = MFMA_B16(qh[ks], b1l, shl[1]);
            slh[1] = MFMA_B16(ql[ks], b1h, slh[1]);
        }
        #pragma unroll
        for (int kf = 0; kf < 2; ++kf) {
            f32x4 sv = shh[kf] + shl[kf] + slh[kf];
            #pragma unroll
            for (int r = 0; r < 4; ++r)
                Ps[w*16 + l16*4 + r][kf*16 + l15] = sv[r];
        }
        // ---- issue V^T loads early (hide HBM under softmax) ----
        bf16x8 vreg[8];
        #pragma unroll
        for (int i = 0; i < 8; ++i) {
            int idx = t + 256*i;
            int f = idx >> 2, c8 = (idx & 3)*8;
            vreg[i] = *(const bf16x8*)&Vg[(size_t)f*SS + k0 + c8];
        }
        __syncthreads();                              // (2) scores ready, K reads done
        #pragma unroll
        for (int i = 0; i < 8; ++i) {
            int idx = t + 256*i;
            int f = idx >> 2, c8 = (idx & 3)*8;
            *(bf16x8*)&Vts[f][c8] = vreg[i];
        }
        // ---- online softmax: 4 threads per row ----
        {
            const int r = t >> 2, sub = t & 3;
            float sv[8];
            float mx = -3.0e38f;
            #pragma unroll
            for (int j = 0; j < 8; ++j) { sv[j] = Ps[r][sub*8 + j]; mx = fmaxf(mx, sv[j]); }
            mx = fmaxf(mx, __shfl_xor(mx, 1, 4));
            mx = fmaxf(mx, __shfl_xor(mx, 2, 4));
            const float mold = mrow[r];
            const float mnew = fmaxf(mold, mx);
            float ls = 0.0f;
            #pragma unroll
            for (int j = 0; j < 8; ++j) {
                float p = __expf(sv[j] - mnew);
                ls += p;
                Pb[r][sub*8 + j] = f2bf(p);
            }
            ls += __shfl_xor(ls, 1, 4);
            ls += __shfl_xor(ls, 2, 4);
            if (sub == 0) {
                float sc = __expf(mold - mnew);
                srow[r] = sc;
                lrow[r] = lrow[r]*sc + ls;
                mrow[r] = mnew;
            }
        }
        __syncthreads();                              // (3) Pb, Vts, srow ready
        // ---- rescale + PV (plain bf16) ----
        #pragma unroll
        for (int mf = 0; mf < 4; ++mf)
        #pragma unroll
        for (int r = 0; r < 4; ++r) {
            float sc = srow[mf*16 + l16*4 + r];
            #pragma unroll
            for (int ff = 0; ff < 8; ++ff) o[mf][ff][r] *= sc;
        }
        bf16x8 pa[4];
        #pragma unroll
        for (int mf = 0; mf < 4; ++mf)
            pa[mf] = *(const bf16x8*)&Pb[mf*16 + l15][l16*8];
        #pragma unroll
        for (int ff = 0; ff < 8; ++ff) {
            bf16x8 vb = *(const bf16x8*)&Vts[w*128 + ff*16 + l15][l16*8];
            #pragma unroll
            for (int mf = 0; mf < 4; ++mf)
                o[mf][ff] = MFMA_B16(pa[mf], vb, o[mf][ff]);
        }
    }
    // ---- epilogue: Z = O/l + x (per-head residual), store hi/lo ----
    const int b = b_base + bh/HH;
    const float* xp = x + ((size_t)b*SS + s0)*FF;
    short* Zh = Zhi + ((size_t)bh*SS + s0)*FF;
    short* Zl = Zlo + ((size_t)bh*SS + s0)*FF;
    #pragma unroll
    for (int mf = 0; mf < 4; ++mf)
    #pragma unroll
    for (int r = 0; r < 4; ++r) {
        const int q = mf*16 + l16*4 + r;
        const float li = 1.0f / lrow[q];
        #pragma unroll
        for (int ff = 0; ff < 8; ++ff) {
            const int col = w*128 + ff*16 + l15;
            float zv = o[mf][ff][r]*li + xp[(size_t)q*FF + col];
            short hh = f2bf(zv);
            Zh[(size_t)q*FF + col] = hh;
            Zl[(size_t)q*FF + col] = f2bf(zv - bf2f(hh));
        }
    }
}

// ============ Kernel 3: joiner GEMM, split-bf16 MFMA -> Jout fp32 ============
// grid (FF/128=4, cb*SS/64), block 256 (2x2 waves of 32x64)
__global__ __launch_bounds__(256,1)
void joiner_kernel(const short* __restrict__ Zhi, const short* __restrict__ Zlo,
                   const short* __restrict__ WjTh, const short* __restrict__ WjTl,
                   float* __restrict__ Jout)
{
    __shared__ short Ah[64][72], Al[64][72];
    __shared__ short Bh[128][72], Bl[128][72];
    const int t = threadIdx.x, lane = t & 63, w = t >> 6;
    const int l15 = lane & 15, l16 = lane >> 4;
    const int wm = (w >> 1)*32, wn = (w & 1)*64;
    const int n0 = blockIdx.x*128, m0 = blockIdx.y*64;
    const int bl = m0 >> 11;
    const int sl = m0 & (SS-1);
    f32x4 acc[2][4] = {};

    for (int k0 = 0; k0 < HH*FF; k0 += 64) {
        const int h = k0 >> 9, f0 = k0 & (FF-1);
        __syncthreads();
        #pragma unroll
        for (int i = 0; i < 2; ++i) {
            int idx = t + 256*i;
            int row = idx >> 3, c8 = (idx & 7)*8;
            size_t g = ((size_t)(bl*HH + h)*SS + sl + row)*FF + f0 + c8;
            *(bf16x8*)&Ah[row][c8] = *(const bf16x8*)&Zhi[g];
            *(bf16x8*)&Al[row][c8] = *(const bf16x8*)&Zlo[g];
        }
        #pragma unroll
        for (int i = 0; i < 4; ++i) {
            int idx = t + 256*i;
            int row = idx >> 3, c8 = (idx & 7)*8;
            size_t g = (size_t)(n0+row)*(HH*FF) + k0 + c8;
            *(bf16x8*)&Bh[row][c8] = *(const bf16x8*)&WjTh[g];
            *(bf16x8*)&Bl[row][c8] = *(const bf16x8*)&WjTl[g];
        }
        __syncthreads();
        #pragma unroll
        for (int ks = 0; ks < 2; ++ks) {
            bf16x8 a_h[2], a_l[2], b_h[4], b_l[4];
            #pragma unroll
            for (int mf = 0; mf < 2; ++mf) {
                a_h[mf] = *(const bf16x8*)&Ah[wm + mf*16 + l15][ks*32 + l16*8];
                a_l[mf] = *(const bf16x8*)&Al[wm + mf*16 + l15][ks*32 + l16*8];
            }
            #pragma unroll
            for (int nf = 0; nf < 4; ++nf) {
                b_h[nf] = *(const bf16x8*)&Bh[wn + nf*16 + l15][ks*32 + l16*8];
                b_l[nf] = *(const bf16x8*)&Bl[wn + nf*16 + l15][ks*32 + l16*8];
            }
            #pragma unroll
            for (int mf = 0; mf < 2; ++mf)
            #pragma unroll
            for (int nf = 0; nf < 4; ++nf) {
                acc[mf][nf] = MFMA_B16(a_h[mf], b_h[nf], acc[mf][nf]);
                acc[mf][nf] = MFMA_B16(a_h[mf], b_l[nf], acc[mf][nf]);
                acc[mf][nf] = MFMA_B16(a_l[mf], b_h[nf], acc[mf][nf]);
            }
        }
    }
    #pragma unroll
    for (int mf = 0; mf < 2; ++mf)
    #pragma unroll
    for (int nf = 0; nf < 4; ++nf)
    #pragma unroll
    for (int r = 0; r < 4; ++r)
        Jout[(size_t)(m0 + wm + mf*16 + l16*4 + r)*FF + n0 + wn + nf*16 + l15] = acc[mf][nf][r];
}

// ============ Kernel 4: residual + LayerNorm ============
// block 256 = 4 rows x 64 lanes; grid cb*SS/4
__global__ __launch_bounds__(256)
void ln_kernel(const float* __restrict__ x, const float* __restrict__ Jout,
               const float* __restrict__ gamma, const float* __restrict__ beta,
               float* __restrict__ out, int b_base)
{
    const int t = threadIdx.x, lane = t & 63;
    const int rl = blockIdx.x*4 + (t >> 6);
    const size_t gr = (size_t)b_base*SS + rl;
    const int c1 = lane*4, c2 = 256 + lane*4;
    float4 j1 = *(const float4*)&Jout[(size_t)rl*FF + c1];
    float4 j2 = *(const float4*)&Jout[(size_t)rl*FF + c2];
    float4 x1 = *(const float4*)&x[gr*FF + c1];
    float4 x2 = *(const float4*)&x[gr*FF + c2];
    float y[8];
    y[0]=j1.x+x1.x; y[1]=j1.y+x1.y; y[2]=j1.z+x1.z; y[3]=j1.w+x1.w;
    y[4]=j2.x+x2.x; y[5]=j2.y+x2.y; y[6]=j2.z+x2.z; y[7]=j2.w+x2.w;
    float s1 = 0.f, s2 = 0.f;
    #pragma unroll
    for (int j = 0; j < 8; ++j) { s1 += y[j]; s2 += y[j]*y[j]; }
    #pragma unroll
    for (int m = 1; m < 64; m <<= 1) {
        s1 += __shfl_xor(s1, m);
        s2 += __shfl_xor(s2, m);
    }
    const float mu = s1 * (1.0f/FF);
    float var = s2 * (1.0f/FF) - mu*mu;
    var = fmaxf(var, 0.0f);
    const float rs = rsqrtf(var + EPSV);
    float4 g1 = *(const float4*)&gamma[c1], g2 = *(const float4*)&gamma[c2];
    float4 b1 = *(const float4*)&beta[c1],  b2 = *(const float4*)&beta[c2];
    float4 o1, o2;
    o1.x = (y[0]-mu)*rs*g1.x + b1.x; o1.y = (y[1]-mu)*rs*g1.y + b1.y;
    o1.z = (y[2]-mu)*rs*g1.z + b1.z; o1.w = (y[3]-mu)*rs*g1.w + b1.w;
    o2.x = (y[4]-mu)*rs*g2.x + b2.x; o2.y = (y[5]-mu)*rs*g2.y + b2.y;
    o2.z = (y[6]-mu)*rs*g2.z + b2.z; o2.w = (y[7]-mu)*rs*g2.w + b2.w;
    *(float4*)&out[gr*FF + c1] = o1;
    *(float4*)&out[gr*FF + c2] = o2;
}

extern "C" void kernel_launch(void* const* d_in, const int* in_sizes, int n_in,
                              void* d_out, int out_size, void* d_ws, size_t ws_size,
                              hipStream_t stream)
{
    const float* x     = (const float*)d_in[0];
    const float* Wq    = (const float*)d_in[1];
    const float* Wk    = (const float*)d_in[2];
    const float* Wv    = (const float*)d_in[3];
    const float* Wj    = (const float*)d_in[4];
    const float* gamma = (const float*)d_in[5];
    const float* beta  = (const float*)d_in[6];
    float* out = (float*)d_out;

    // ---- workspace carve (bf16 planes as short) ----
    short* p = (short*)d_ws;
    short* xhi = p;  p += (size_t)BB*SS*FF;
    short* xlo = p;  p += (size_t)BB*SS*FF;
    short* Wth = p;  p += (size_t)3*HH*FF*FF;
    short* Wtl = p;  p += (size_t)3*HH*FF*FF;
    short* WjTh = p; p += (size_t)HH*FF*FF;
    short* WjTl = p; p += (size_t)HH*FF*FF;
    short* chunk0 = p;

    const size_t head_bytes = (size_t)(chunk0 - (short*)d_ws) * sizeof(short);
    const size_t plane_sh = (size_t)HH*SS*FF;                     // shorts/batch/plane
    const size_t per_batch_bytes = 7*plane_sh*sizeof(short) + (size_t)SS*FF*sizeof(float);
    int nb = 1;
    if (ws_size > head_bytes) {
        size_t m = (ws_size - head_bytes) / per_batch_bytes;
        nb = (m < 1) ? 1 : (m > BB ? BB : (int)m);
    }

    // ---- one-time preps ----
    prep_x_kernel<<<2048, 256, 0, stream>>>(x, xhi, xlo);
    prep_t_kernel<<<dim3(8,8,HH), 256, 0, stream>>>(Wq, Wth,                        Wtl,                        FF, FF);
    prep_t_kernel<<<dim3(8,8,HH), 256, 0, stream>>>(Wk, Wth + (size_t)HH*FF*FF,     Wtl + (size_t)HH*FF*FF,     FF, FF);
    prep_t_kernel<<<dim3(8,8,HH), 256, 0, stream>>>(Wv, Wth + (size_t)2*HH*FF*FF,   Wtl + (size_t)2*HH*FF*FF,   FF, FF);
    prep_t_kernel<<<dim3(8,64,1), 256, 0, stream>>>(Wj, WjTh, WjTl, HH*FF, FF);

    for (int b_base = 0; b_base < BB; b_base += nb) {
        int cb = (BB - b_base < nb) ? (BB - b_base) : nb;
        size_t pp = (size_t)cb*plane_sh;
        short* Qhi = chunk0;
        short* Qlo = Qhi + pp;
        short* Khi = Qlo + pp;
        short* Klo = Khi + pp;
        short* Vt  = Klo + pp;
        short* Zhi = Vt  + pp;
        short* Zlo = Zhi + pp;
        float* Jout = (float*)(Zlo + pp);
        const int nbh = cb*HH;

        proj_kernel<<<dim3(4,16,3*nbh), 256, 0, stream>>>(xhi, xlo, Wth, Wtl,
                                                          Qhi, Qlo, Khi, Klo, Vt, b_base, nbh);
        attn_kernel<<<dim3(SS/64, nbh), 256, 0, stream>>>(x, Qhi, Qlo, Khi, Klo, Vt,
                                                          Zhi, Zlo, b_base);
        joiner_kernel<<<dim3(4, cb*SS/64), 256, 0, stream>>>(Zhi, Zlo, WjTh, WjTl, Jout);
        ln_kernel<<<cb*SS/4, 256, 0, stream>>>(x, Jout, gamma, beta, out, b_base);
    }
}